// Round 5
// baseline (834.382 us; speedup 1.0000x reference)
//
#include <hip/hip_runtime.h>
#include <hip/hip_bf16.h>
#include <cstdint>

#define BB 32
#define NN 577
#define CC 768
#define HH 12
#define HIDN 3072
#define MROWS (BB*NN)   // 18464

typedef __attribute__((ext_vector_type(8))) short bf16x8;   // 8 bf16 = 4 VGPRs
typedef __attribute__((ext_vector_type(4))) float f32x4;

__device__ __forceinline__ float b2f(unsigned short u) {
    union { float f; unsigned int i; } x; x.i = ((unsigned int)u) << 16; return x.f;
}
__device__ __forceinline__ unsigned short f2b(float f) {
    union { float f; unsigned int i; } x; x.f = f;
    unsigned int i = x.i;
    i += 0x7fffu + ((i >> 16) & 1u);   // round-to-nearest-even
    return (unsigned short)(i >> 16);
}

__device__ __forceinline__ void async16(const void* g, void* l) {
    __builtin_amdgcn_global_load_lds(
        (const __attribute__((address_space(1))) uint32_t*)g,
        (__attribute__((address_space(3))) uint32_t*)l, 16, 0, 0);
}

// Fast exact-GELU: erf via Abramowitz-Stegun 7.1.26 (|err|<=1.5e-7),
// rcp + exp are single HW instrs. ~13 VALU vs ~45 for libm erff.
__device__ __forceinline__ float gelu_f(float v) {
    float ax = fabsf(v) * 0.70710678118654752f;
    float t = __builtin_amdgcn_rcpf(1.0f + 0.3275911f * ax);
    float poly = t * (0.254829592f + t * (-0.284496736f + t * (1.421413741f +
                 t * (-1.453152027f + t * 1.061405429f))));
    float e = __expf(-ax * ax);
    float erf_abs = 1.0f - poly * e;
    float erf_v = (v >= 0.f) ? erf_abs : -erf_abs;
    return 0.5f * v * (1.0f + erf_v);
}

// ---------------------------------------------------------------------------
// fp32 -> bf16 weight conversion (4 matrices in one kernel)
// ---------------------------------------------------------------------------
__global__ void cvt4(const float* __restrict__ a, int na, unsigned short* __restrict__ oa,
                     const float* __restrict__ b, int nb, unsigned short* __restrict__ ob,
                     const float* __restrict__ c, int nc, unsigned short* __restrict__ oc,
                     const float* __restrict__ d, int nd, unsigned short* __restrict__ od) {
    int stride = gridDim.x * blockDim.x;
    int t = blockIdx.x * blockDim.x + threadIdx.x;
    for (int i = t; i < na; i += stride) oa[i] = f2b(a[i]);
    for (int i = t; i < nb; i += stride) ob[i] = f2b(b[i]);
    for (int i = t; i < nc; i += stride) oc[i] = f2b(c[i]);
    for (int i = t; i < nd; i += stride) od[i] = f2b(d[i]);
}

// ---------------------------------------------------------------------------
// LayerNorm (row of 768), fp32 in -> bf16 out
// ---------------------------------------------------------------------------
__global__ __launch_bounds__(256)
void ln_kernel(const float* __restrict__ x, const float* __restrict__ w,
               const float* __restrict__ bsv, unsigned short* __restrict__ out) {
    int row = blockIdx.x;
    const float* xr = x + (size_t)row * CC;
    float v[3]; float s = 0.f, ss = 0.f;
    #pragma unroll
    for (int i = 0; i < 3; ++i) {
        v[i] = xr[threadIdx.x + i * 256];
        s += v[i]; ss += v[i] * v[i];
    }
    int lane = threadIdx.x & 63, wv = threadIdx.x >> 6;
    #pragma unroll
    for (int off = 32; off; off >>= 1) { s += __shfl_down(s, off); ss += __shfl_down(ss, off); }
    __shared__ float rs[4], rss[4];
    __shared__ float mean_s, rstd_s;
    if (lane == 0) { rs[wv] = s; rss[wv] = ss; }
    __syncthreads();
    if (threadIdx.x == 0) {
        float S = rs[0] + rs[1] + rs[2] + rs[3];
        float SS = rss[0] + rss[1] + rss[2] + rss[3];
        float m = S * (1.0f / 768.0f);
        float var = SS * (1.0f / 768.0f) - m * m;
        mean_s = m; rstd_s = rsqrtf(var + 1e-6f);
    }
    __syncthreads();
    float m = mean_s, r = rstd_s;
    #pragma unroll
    for (int i = 0; i < 3; ++i) {
        int c = threadIdx.x + i * 256;
        out[(size_t)row * CC + c] = f2b((v[i] - m) * r * w[c] + bsv[c]);
    }
}

// ---------------------------------------------------------------------------
// bf16 GEMM: out = epilogue(A(M,K) @ Bw(N,K)^T + bias)
// m97 structure: 128x128 tile, BK=32, global_load_lds w=16, mfma 16x16x32 bf16
// EPI 0: bf16 store | 1: fast exact GELU -> bf16 | 2: fp32 store w/ residual
// XCD swizzle: n-tiles sharing an m-row get block IDs == same value mod 8 so
// they land on one XCD -> A k-slices stay L2-resident (kills A over-fetch).
// Launch grid dim3(NT, 152): 152 = 8*ceil(145/8) padded m-rows.
// ---------------------------------------------------------------------------
template <int EPI>
__global__ __launch_bounds__(256)
void gemm_bt(const unsigned short* __restrict__ A, const unsigned short* __restrict__ Bw,
             const float* __restrict__ bias, const float* __restrict__ resid,
             unsigned short* __restrict__ outb, float* __restrict__ outf,
             int M, int N, int K) {
    const int NT = gridDim.x;
    const int MT = (M + 127) >> 7;
    {
        // dispatch-order flat id -> (m_tile, n_tile) with same-XCD A sharing
        int flat = blockIdx.y * NT + blockIdx.x;
        int xcd = flat & 7, s = flat >> 3;
        int n_t = s % NT, mj = s / NT;
        int m_t = xcd + 8 * mj;
        if (m_t >= MT) return;
        // reuse names below
        const int m0 = m_t * 128, n0 = n_t * 128;

        __shared__ __align__(16) unsigned short As[128 * 32];
        __shared__ __align__(16) unsigned short Bs[128 * 32];
        const int tid = threadIdx.x;
        const int wave = tid >> 6, lane = tid & 63;
        const int wr = wave >> 1, wc = wave & 1;
        const int quad = lane >> 4, l16 = lane & 15;

        f32x4 acc[4][4] = {};

        for (int k0 = 0; k0 < K; k0 += 32) {
            #pragma unroll
            for (int i = 0; i < 2; ++i) {
                int c = i * 256 + tid;
                int row = c >> 2, seg = c & 3;
                int gm = m0 + row; if (gm > M - 1) gm = M - 1;   // clamp ragged M
                async16(A + (size_t)gm * K + k0 + seg * 8, &As[c * 8]);
                int gn = n0 + row;                                // N multiple of 128
                async16(Bw + (size_t)gn * K + k0 + seg * 8, &Bs[c * 8]);
            }
            __syncthreads();
            bf16x8 af[4], bfr[4];
            #pragma unroll
            for (int mi = 0; mi < 4; ++mi)
                af[mi] = *(const bf16x8*)&As[(wr * 64 + mi * 16 + l16) * 32 + quad * 8];
            #pragma unroll
            for (int ni = 0; ni < 4; ++ni)
                bfr[ni] = *(const bf16x8*)&Bs[(wc * 64 + ni * 16 + l16) * 32 + quad * 8];
            #pragma unroll
            for (int mi = 0; mi < 4; ++mi)
                #pragma unroll
                for (int ni = 0; ni < 4; ++ni)
                    acc[mi][ni] = __builtin_amdgcn_mfma_f32_16x16x32_bf16(af[mi], bfr[ni], acc[mi][ni], 0, 0, 0);
            __syncthreads();
        }

        #pragma unroll
        for (int mi = 0; mi < 4; ++mi) {
            #pragma unroll
            for (int r = 0; r < 4; ++r) {
                int grow = m0 + wr * 64 + mi * 16 + quad * 4 + r;   // C/D: row=quad*4+reg
                if (grow >= M) continue;
                #pragma unroll
                for (int ni = 0; ni < 4; ++ni) {
                    int gcol = n0 + wc * 64 + ni * 16 + l16;        // C/D: col=lane&15
                    float v = acc[mi][ni][r] + bias[gcol];
                    size_t idx = (size_t)grow * N + gcol;
                    if (EPI == 0) {
                        outb[idx] = f2b(v);
                    } else if (EPI == 1) {
                        outb[idx] = f2b(gelu_f(v));
                    } else {
                        outf[idx] = resid[idx] + v;
                    }
                }
            }
        }
    }
}

// ---------------------------------------------------------------------------
// MFMA flash attention, v2.1. One block = (b, h, 64 q rows); 4 waves x 16 rows.
// Vt uses a key-group XOR swizzle (group' = (key>>3) ^ (d>>3)) so the
// transpose's u16 writes are bank-conflict-free (was 16-way); reads remain
// aligned b128 at the same cost.
// ---------------------------------------------------------------------------
__global__ __launch_bounds__(256)
void attn_mfma(const unsigned short* __restrict__ qkv, const float* __restrict__ aw,
               unsigned short* __restrict__ O, float* __restrict__ patch) {
    const int qt = blockIdx.x, h = blockIdx.y, b = blockIdx.z;
    const int tid = threadIdx.x, wv = tid >> 6, lane = tid & 63;
    const int quad = lane >> 4, l16 = lane & 15;

    __shared__ __align__(16) unsigned short Ks[64 * 72];
    __shared__ __align__(16) unsigned short Vt[64 * 72];
    __shared__ __align__(16) unsigned short Pt[4][64 * 18];
    __shared__ __align__(16) float Sw[4][16 * 68];

    // Q fragment (A-layout: m=l16, k=quad*8+j), resident all kernel.
    int qrow = qt * 64 + wv * 16 + l16;
    int qclamp = qrow < NN ? qrow : NN - 1;
    const unsigned short* qbase = qkv + (size_t)(b * NN + qclamp) * 2304 + h * 64;
    bf16x8 qf[2];
    qf[0] = *(const bf16x8*)(qbase + quad * 8);
    qf[1] = *(const bf16x8*)(qbase + 32 + quad * 8);

    f32x4 o[4] = {};          // O accumulator, C-layout (row=quad*4+r, col d=ni*16+l16)
    float mst = -1.0e30f;     // running max for row l16 (replicated across quads)
    float lst = 0.f;          // running denom for row l16

    for (int kt = 0; kt < 10; ++kt) {
        __syncthreads();   // previous tile's Ks/Vt reads done before overwrite
        // ---- stage K tile [key][d] and V tile transposed+swizzled [d][key'] ----
        #pragma unroll
        for (int i = 0; i < 2; ++i) {
            int c = i * 256 + tid;
            int key = c >> 3, seg = c & 7;           // 8 segs of 8 bf16 per 64-elem row
            int gk = kt * 64 + key; if (gk >= NN) gk = NN - 1;
            const unsigned short* kb = qkv + (size_t)(b * NN + gk) * 2304 + 768 + h * 64 + seg * 8;
            bf16x8 kv = *(const bf16x8*)kb;
            *(bf16x8*)&Ks[key * 72 + seg * 8] = kv;
            const unsigned short* vb = qkv + (size_t)(b * NN + gk) * 2304 + 1536 + h * 64 + seg * 8;
            bf16x8 vvv = *(const bf16x8*)vb;
            int kg = key >> 3, kl = key & 7;
            int swz = (kg ^ seg) * 8 + kl;           // d>>3 == seg for d=seg*8+e
            #pragma unroll
            for (int e = 0; e < 8; ++e)
                Vt[(seg * 8 + e) * 72 + swz] = ((const unsigned short*)&vvv)[e];
        }
        __syncthreads();

        // ---- S = Q K^T  (16 q x 64 keys per wave) ----
        f32x4 s[4];
        #pragma unroll
        for (int ni = 0; ni < 4; ++ni) {
            bf16x8 b0 = *(const bf16x8*)&Ks[(ni * 16 + l16) * 72 + quad * 8];
            bf16x8 b1 = *(const bf16x8*)&Ks[(ni * 16 + l16) * 72 + 32 + quad * 8];
            f32x4 acc = {};
            acc = __builtin_amdgcn_mfma_f32_16x16x32_bf16(qf[0], b0, acc, 0, 0, 0);
            acc = __builtin_amdgcn_mfma_f32_16x16x32_bf16(qf[1], b1, acc, 0, 0, 0);
            s[ni] = acc;
        }

        // ---- store scores (scaled) to Sw via verified C/D mapping ----
        float* SwW = Sw[wv];
        #pragma unroll
        for (int ni = 0; ni < 4; ++ni)
            #pragma unroll
            for (int r = 0; r < 4; ++r)
                SwW[(quad * 4 + r) * 68 + ni * 16 + l16] = s[ni][r] * 0.125f;

        // ---- mask invalid keys (only last tile has any) ----
        if (kt == 9) {
            #pragma unroll
            for (int j = 0; j < 16; ++j) {
                int gkey = kt * 64 + quad * 16 + j;
                if (gkey >= NN) SwW[l16 * 68 + quad * 16 + j] = -1.0e30f;
            }
        }

        // ---- row 0 only: patch_attn extraction + attn_weight factor ----
        if (qt == 0 && wv == 0 && l16 == 0) {
            #pragma unroll
            for (int j = 0; j < 16; ++j) {
                int gkey = kt * 64 + quad * 16 + j;
                if (gkey >= 1 && gkey < NN) {
                    float v = SwW[0 * 68 + quad * 16 + j];
                    patch[(size_t)(b * HH + h) * (NN - 1) + gkey - 1] = v;
                    float f = aw[b * (NN - 1) + gkey - 1] * 0.1f + 0.9f;
                    SwW[0 * 68 + quad * 16 + j] = v * f;
                }
            }
        }

        // ---- online softmax: lane owns row l16, keys quad*16..+15 ----
        const float* Srow = &SwW[l16 * 68];
        float tm = -1.0e30f;
        #pragma unroll
        for (int j = 0; j < 16; ++j) tm = fmaxf(tm, Srow[quad * 16 + j]);
        tm = fmaxf(tm, __shfl_xor(tm, 16));
        tm = fmaxf(tm, __shfl_xor(tm, 32));
        float nm = fmaxf(mst, tm);
        float alpha = __expf(mst - nm);     // first tile: exp(-1e30) -> 0
        mst = nm;
        float rsum = 0.f;
        #pragma unroll
        for (int j = 0; j < 16; ++j) {
            float p = __expf(Srow[quad * 16 + j] - nm);   // masked: exp(-1e30) -> 0
            Pt[wv][(quad * 16 + j) * 18 + l16] = f2b(p);
            rsum += p;
        }
        rsum += __shfl_xor(rsum, 16);
        rsum += __shfl_xor(rsum, 32);
        lst = lst * alpha + rsum;

        // ---- rescale O rows by alpha (alpha for row quad*4+r from lane quad*4+r) ----
        #pragma unroll
        for (int r = 0; r < 4; ++r) {
            float ar = __shfl(alpha, quad * 4 + r);
            #pragma unroll
            for (int ni = 0; ni < 4; ++ni) o[ni][r] *= ar;
        }

        // ---- O += P V ----
        #pragma unroll
        for (int kc = 0; kc < 2; ++kc) {
            union { bf16x8 v; unsigned short u[8]; } af;
            #pragma unroll
            for (int j = 0; j < 8; ++j)
                af.u[j] = Pt[wv][(kc * 32 + quad * 8 + j) * 18 + l16];
            #pragma unroll
            for (int ni = 0; ni < 4; ++ni) {
                int d = ni * 16 + l16;
                int gs = (kc * 4 + quad) ^ (d >> 3);   // un-swizzle key group
                bf16x8 vf = *(const bf16x8*)&Vt[d * 72 + gs * 8];
                o[ni] = __builtin_amdgcn_mfma_f32_16x16x32_bf16(af.v, vf, o[ni], 0, 0, 0);
            }
        }
    }

    // ---- finalize: O /= l (l for row quad*4+r from lane quad*4+r), store bf16 ----
    #pragma unroll
    for (int r = 0; r < 4; ++r) {
        float lr = __shfl(lst, quad * 4 + r);
        float inv = (lr > 0.f) ? __builtin_amdgcn_rcpf(lr) : 0.f;
        int row = qt * 64 + wv * 16 + quad * 4 + r;
        if (row < NN) {
            #pragma unroll
            for (int ni = 0; ni < 4; ++ni)
                O[(size_t)(b * NN + row) * CC + h * 64 + ni * 16 + l16] = f2b(o[ni][r] * inv);
        }
    }
}

// ---------------------------------------------------------------------------
extern "C" void kernel_launch(void* const* d_in, const int* in_sizes, int n_in,
                              void* d_out, int out_size, void* d_ws, size_t ws_size,
                              hipStream_t stream) {
    const float* x       = (const float*)d_in[0];
    const float* aw      = (const float*)d_in[1];
    const float* ln1w    = (const float*)d_in[2];
    const float* ln1b    = (const float*)d_in[3];
    const float* qkvw_f  = (const float*)d_in[4];
    const float* qkvb    = (const float*)d_in[5];
    const float* projw_f = (const float*)d_in[6];
    const float* projb   = (const float*)d_in[7];
    const float* ln2w    = (const float*)d_in[8];
    const float* ln2b    = (const float*)d_in[9];
    const float* fc1w_f  = (const float*)d_in[10];
    const float* fc1b    = (const float*)d_in[11];
    const float* fc2w_f  = (const float*)d_in[12];
    const float* fc2b    = (const float*)d_in[13];

    // workspace layout (g1 aliases h_bf+qkv, both dead before FC1). ~240 MB.
    char* ws = (char*)d_ws;
    unsigned short* h_bf  = (unsigned short*)(ws + 0);            // 18464x768 bf16
    unsigned short* qkv   = (unsigned short*)(ws + 28360704);     // 18464x2304 bf16
    unsigned short* g1    = (unsigned short*)(ws + 0);            // 18464x3072 bf16 (alias)
    unsigned short* attno = (unsigned short*)(ws + 113442816);    // 18464x768 bf16
    float*          x1    = (float*)(ws + 141803520);             // 18464x768 f32
    unsigned short* h2    = (unsigned short*)(ws + 198524928);    // 18464x768 bf16
    unsigned short* qkvw  = (unsigned short*)(ws + 226885632);    // 2304x768 bf16
    unsigned short* projw = (unsigned short*)(ws + 230424576);    // 768x768 bf16
    unsigned short* fc1w  = (unsigned short*)(ws + 231604224);    // 3072x768 bf16
    unsigned short* fc2w  = (unsigned short*)(ws + 236322816);    // 768x3072 bf16

    float* out_x = (float*)d_out;
    float* out_patch = out_x + (size_t)MROWS * CC;

    // 152 = 8 * ceil(145 m-tiles / 8) -- padded for the XCD swizzle
    cvt4<<<1024, 256, 0, stream>>>(qkvw_f, 2304 * 768, qkvw,
                                   projw_f, 768 * 768, projw,
                                   fc1w_f, 3072 * 768, fc1w,
                                   fc2w_f, 768 * 3072, fc2w);
    ln_kernel<<<MROWS, 256, 0, stream>>>(x, ln1w, ln1b, h_bf);
    gemm_bt<0><<<dim3(18, 152), 256, 0, stream>>>(h_bf, qkvw, qkvb, nullptr, qkv, nullptr,
                                                  MROWS, 2304, 768);
    attn_mfma<<<dim3(10, HH, BB), 256, 0, stream>>>(qkv, aw, attno, out_patch);
    gemm_bt<2><<<dim3(6, 152), 256, 0, stream>>>(attno, projw, projb, x, nullptr, x1,
                                                 MROWS, 768, 768);
    ln_kernel<<<MROWS, 256, 0, stream>>>(x1, ln2w, ln2b, h2);
    gemm_bt<1><<<dim3(24, 152), 256, 0, stream>>>(h2, fc1w, fc1b, nullptr, g1, nullptr,
                                                  MROWS, 3072, 768);
    gemm_bt<2><<<dim3(6, 152), 256, 0, stream>>>(g1, fc2w, fc2b, x1, nullptr, out_x,
                                                 MROWS, 768, 3072);
}

// Round 6
// 782.228 us; speedup vs baseline: 1.0667x; 1.0667x over previous
//
#include <hip/hip_runtime.h>
#include <hip/hip_bf16.h>
#include <cstdint>

#define BB 32
#define NN 577
#define CC 768
#define HH 12
#define HIDN 3072
#define MROWS (BB*NN)   // 18464

typedef __attribute__((ext_vector_type(8))) short bf16x8;   // 8 bf16 = 4 VGPRs
typedef __attribute__((ext_vector_type(4))) float f32x4;

__device__ __forceinline__ float b2f(unsigned short u) {
    union { float f; unsigned int i; } x; x.i = ((unsigned int)u) << 16; return x.f;
}
__device__ __forceinline__ unsigned short f2b(float f) {
    union { float f; unsigned int i; } x; x.f = f;
    unsigned int i = x.i;
    i += 0x7fffu + ((i >> 16) & 1u);   // round-to-nearest-even
    return (unsigned short)(i >> 16);
}

__device__ __forceinline__ void async16(const void* g, void* l) {
    __builtin_amdgcn_global_load_lds(
        (const __attribute__((address_space(1))) uint32_t*)g,
        (__attribute__((address_space(3))) uint32_t*)l, 16, 0, 0);
}

// Fast exact-GELU: erf via Abramowitz-Stegun 7.1.26 (|err|<=1.5e-7),
// rcp + exp are single HW instrs. ~13 VALU vs ~45 for libm erff.
__device__ __forceinline__ float gelu_f(float v) {
    float ax = fabsf(v) * 0.70710678118654752f;
    float t = __builtin_amdgcn_rcpf(1.0f + 0.3275911f * ax);
    float poly = t * (0.254829592f + t * (-0.284496736f + t * (1.421413741f +
                 t * (-1.453152027f + t * 1.061405429f))));
    float e = __expf(-ax * ax);
    float erf_abs = 1.0f - poly * e;
    float erf_v = (v >= 0.f) ? erf_abs : -erf_abs;
    return 0.5f * v * (1.0f + erf_v);
}

// ---------------------------------------------------------------------------
// fp32 -> bf16 weight conversion (4 matrices in one kernel)
// ---------------------------------------------------------------------------
__global__ void cvt4(const float* __restrict__ a, int na, unsigned short* __restrict__ oa,
                     const float* __restrict__ b, int nb, unsigned short* __restrict__ ob,
                     const float* __restrict__ c, int nc, unsigned short* __restrict__ oc,
                     const float* __restrict__ d, int nd, unsigned short* __restrict__ od) {
    int stride = gridDim.x * blockDim.x;
    int t = blockIdx.x * blockDim.x + threadIdx.x;
    for (int i = t; i < na; i += stride) oa[i] = f2b(a[i]);
    for (int i = t; i < nb; i += stride) ob[i] = f2b(b[i]);
    for (int i = t; i < nc; i += stride) oc[i] = f2b(c[i]);
    for (int i = t; i < nd; i += stride) od[i] = f2b(d[i]);
}

// ---------------------------------------------------------------------------
// LayerNorm (row of 768), fp32 in -> bf16 out
// ---------------------------------------------------------------------------
__global__ __launch_bounds__(256)
void ln_kernel(const float* __restrict__ x, const float* __restrict__ w,
               const float* __restrict__ bsv, unsigned short* __restrict__ out) {
    int row = blockIdx.x;
    const float* xr = x + (size_t)row * CC;
    float v[3]; float s = 0.f, ss = 0.f;
    #pragma unroll
    for (int i = 0; i < 3; ++i) {
        v[i] = xr[threadIdx.x + i * 256];
        s += v[i]; ss += v[i] * v[i];
    }
    int lane = threadIdx.x & 63, wv = threadIdx.x >> 6;
    #pragma unroll
    for (int off = 32; off; off >>= 1) { s += __shfl_down(s, off); ss += __shfl_down(ss, off); }
    __shared__ float rs[4], rss[4];
    __shared__ float mean_s, rstd_s;
    if (lane == 0) { rs[wv] = s; rss[wv] = ss; }
    __syncthreads();
    if (threadIdx.x == 0) {
        float S = rs[0] + rs[1] + rs[2] + rs[3];
        float SS = rss[0] + rss[1] + rss[2] + rss[3];
        float m = S * (1.0f / 768.0f);
        float var = SS * (1.0f / 768.0f) - m * m;
        mean_s = m; rstd_s = rsqrtf(var + 1e-6f);
    }
    __syncthreads();
    float m = mean_s, r = rstd_s;
    #pragma unroll
    for (int i = 0; i < 3; ++i) {
        int c = threadIdx.x + i * 256;
        out[(size_t)row * CC + c] = f2b((v[i] - m) * r * w[c] + bsv[c]);
    }
}

// ---------------------------------------------------------------------------
// bf16 GEMM: out = epilogue(A(M,K) @ Bw(N,K)^T + bias)
// m97 structure, BK=64 as two 32-wide panels (As[2]/Bs[2], 32 KB LDS):
// halves the vmcnt(0)+barrier drains per FLOP; per-panel LDS indexing is
// byte-identical to the verified m97 pattern. K must be a multiple of 64.
// EPI 0: bf16 store | 1: fast exact GELU -> bf16 | 2: fp32 store w/ residual
// XCD swizzle: n-tiles sharing an m-row get block IDs == same value mod 8 so
// they land on one XCD -> A k-slices stay L2-resident (FETCH near-ideal, R4).
// Launch grid dim3(NT, 152): 152 = 8*ceil(145/8) padded m-rows.
// ---------------------------------------------------------------------------
template <int EPI>
__global__ __launch_bounds__(256)
void gemm_bt(const unsigned short* __restrict__ A, const unsigned short* __restrict__ Bw,
             const float* __restrict__ bias, const float* __restrict__ resid,
             unsigned short* __restrict__ outb, float* __restrict__ outf,
             int M, int N, int K) {
    const int NT = gridDim.x;
    const int MT = (M + 127) >> 7;
    // dispatch-order flat id -> (m_tile, n_tile) with same-XCD A sharing
    int flat = blockIdx.y * NT + blockIdx.x;
    int xcd = flat & 7, s = flat >> 3;
    int n_t = s % NT, mj = s / NT;
    int m_t = xcd + 8 * mj;
    if (m_t >= MT) return;
    const int m0 = m_t * 128, n0 = n_t * 128;

    __shared__ __align__(16) unsigned short As[2][128 * 32];
    __shared__ __align__(16) unsigned short Bs[2][128 * 32];
    const int tid = threadIdx.x;
    const int wave = tid >> 6, lane = tid & 63;
    const int wr = wave >> 1, wc = wave & 1;
    const int quad = lane >> 4, l16 = lane & 15;

    f32x4 acc[4][4] = {};

    // per-thread staging coords (fixed across K): two chunks per panel/matrix
    const int c0 = tid, c1 = 256 + tid;
    const int row0 = c0 >> 2, seg0 = c0 & 3;
    const int row1 = c1 >> 2, seg1 = c1 & 3;
    int gm0 = m0 + row0; if (gm0 > M - 1) gm0 = M - 1;
    int gm1 = m0 + row1; if (gm1 > M - 1) gm1 = M - 1;
    const unsigned short* a0 = A + (size_t)gm0 * K + seg0 * 8;
    const unsigned short* a1 = A + (size_t)gm1 * K + seg1 * 8;
    const unsigned short* b0 = Bw + (size_t)(n0 + row0) * K + seg0 * 8;
    const unsigned short* b1 = Bw + (size_t)(n0 + row1) * K + seg1 * 8;

    for (int k0 = 0; k0 < K; k0 += 64) {
        #pragma unroll
        for (int p = 0; p < 2; ++p) {
            int kk = k0 + p * 32;
            async16(a0 + kk, &As[p][c0 * 8]);
            async16(a1 + kk, &As[p][c1 * 8]);
            async16(b0 + kk, &Bs[p][c0 * 8]);
            async16(b1 + kk, &Bs[p][c1 * 8]);
        }
        __syncthreads();
        #pragma unroll
        for (int p = 0; p < 2; ++p) {
            bf16x8 af[4], bfr[4];
            #pragma unroll
            for (int mi = 0; mi < 4; ++mi)
                af[mi] = *(const bf16x8*)&As[p][(wr * 64 + mi * 16 + l16) * 32 + quad * 8];
            #pragma unroll
            for (int ni = 0; ni < 4; ++ni)
                bfr[ni] = *(const bf16x8*)&Bs[p][(wc * 64 + ni * 16 + l16) * 32 + quad * 8];
            #pragma unroll
            for (int mi = 0; mi < 4; ++mi)
                #pragma unroll
                for (int ni = 0; ni < 4; ++ni)
                    acc[mi][ni] = __builtin_amdgcn_mfma_f32_16x16x32_bf16(af[mi], bfr[ni], acc[mi][ni], 0, 0, 0);
        }
        __syncthreads();
    }

    #pragma unroll
    for (int mi = 0; mi < 4; ++mi) {
        #pragma unroll
        for (int r = 0; r < 4; ++r) {
            int grow = m0 + wr * 64 + mi * 16 + quad * 4 + r;   // C/D: row=quad*4+reg
            if (grow >= M) continue;
            #pragma unroll
            for (int ni = 0; ni < 4; ++ni) {
                int gcol = n0 + wc * 64 + ni * 16 + l16;        // C/D: col=lane&15
                float v = acc[mi][ni][r] + bias[gcol];
                size_t idx = (size_t)grow * N + gcol;
                if (EPI == 0) {
                    outb[idx] = f2b(v);
                } else if (EPI == 1) {
                    outb[idx] = f2b(gelu_f(v));
                } else {
                    outf[idx] = resid[idx] + v;
                }
            }
        }
    }
}

// ---------------------------------------------------------------------------
// MFMA flash attention, v2.1. One block = (b, h, 64 q rows); 4 waves x 16 rows.
// Vt uses a key-group XOR swizzle (group' = (key>>3) ^ (d>>3)) so the
// transpose's u16 writes are bank-conflict-free (was 16-way); reads remain
// aligned b128 at the same cost.
// ---------------------------------------------------------------------------
__global__ __launch_bounds__(256)
void attn_mfma(const unsigned short* __restrict__ qkv, const float* __restrict__ aw,
               unsigned short* __restrict__ O, float* __restrict__ patch) {
    const int qt = blockIdx.x, h = blockIdx.y, b = blockIdx.z;
    const int tid = threadIdx.x, wv = tid >> 6, lane = tid & 63;
    const int quad = lane >> 4, l16 = lane & 15;

    __shared__ __align__(16) unsigned short Ks[64 * 72];
    __shared__ __align__(16) unsigned short Vt[64 * 72];
    __shared__ __align__(16) unsigned short Pt[4][64 * 18];
    __shared__ __align__(16) float Sw[4][16 * 68];

    // Q fragment (A-layout: m=l16, k=quad*8+j), resident all kernel.
    int qrow = qt * 64 + wv * 16 + l16;
    int qclamp = qrow < NN ? qrow : NN - 1;
    const unsigned short* qbase = qkv + (size_t)(b * NN + qclamp) * 2304 + h * 64;
    bf16x8 qf[2];
    qf[0] = *(const bf16x8*)(qbase + quad * 8);
    qf[1] = *(const bf16x8*)(qbase + 32 + quad * 8);

    f32x4 o[4] = {};          // O accumulator, C-layout (row=quad*4+r, col d=ni*16+l16)
    float mst = -1.0e30f;     // running max for row l16 (replicated across quads)
    float lst = 0.f;          // running denom for row l16

    for (int kt = 0; kt < 10; ++kt) {
        __syncthreads();   // previous tile's Ks/Vt reads done before overwrite
        // ---- stage K tile [key][d] and V tile transposed+swizzled [d][key'] ----
        #pragma unroll
        for (int i = 0; i < 2; ++i) {
            int c = i * 256 + tid;
            int key = c >> 3, seg = c & 7;           // 8 segs of 8 bf16 per 64-elem row
            int gk = kt * 64 + key; if (gk >= NN) gk = NN - 1;
            const unsigned short* kb = qkv + (size_t)(b * NN + gk) * 2304 + 768 + h * 64 + seg * 8;
            bf16x8 kv = *(const bf16x8*)kb;
            *(bf16x8*)&Ks[key * 72 + seg * 8] = kv;
            const unsigned short* vb = qkv + (size_t)(b * NN + gk) * 2304 + 1536 + h * 64 + seg * 8;
            bf16x8 vvv = *(const bf16x8*)vb;
            int kg = key >> 3, kl = key & 7;
            int swz = (kg ^ seg) * 8 + kl;           // d>>3 == seg for d=seg*8+e
            #pragma unroll
            for (int e = 0; e < 8; ++e)
                Vt[(seg * 8 + e) * 72 + swz] = ((const unsigned short*)&vvv)[e];
        }
        __syncthreads();

        // ---- S = Q K^T  (16 q x 64 keys per wave) ----
        f32x4 s[4];
        #pragma unroll
        for (int ni = 0; ni < 4; ++ni) {
            bf16x8 b0 = *(const bf16x8*)&Ks[(ni * 16 + l16) * 72 + quad * 8];
            bf16x8 b1 = *(const bf16x8*)&Ks[(ni * 16 + l16) * 72 + 32 + quad * 8];
            f32x4 acc = {};
            acc = __builtin_amdgcn_mfma_f32_16x16x32_bf16(qf[0], b0, acc, 0, 0, 0);
            acc = __builtin_amdgcn_mfma_f32_16x16x32_bf16(qf[1], b1, acc, 0, 0, 0);
            s[ni] = acc;
        }

        // ---- store scores (scaled) to Sw via verified C/D mapping ----
        float* SwW = Sw[wv];
        #pragma unroll
        for (int ni = 0; ni < 4; ++ni)
            #pragma unroll
            for (int r = 0; r < 4; ++r)
                SwW[(quad * 4 + r) * 68 + ni * 16 + l16] = s[ni][r] * 0.125f;

        // ---- mask invalid keys (only last tile has any) ----
        if (kt == 9) {
            #pragma unroll
            for (int j = 0; j < 16; ++j) {
                int gkey = kt * 64 + quad * 16 + j;
                if (gkey >= NN) SwW[l16 * 68 + quad * 16 + j] = -1.0e30f;
            }
        }

        // ---- row 0 only: patch_attn extraction + attn_weight factor ----
        if (qt == 0 && wv == 0 && l16 == 0) {
            #pragma unroll
            for (int j = 0; j < 16; ++j) {
                int gkey = kt * 64 + quad * 16 + j;
                if (gkey >= 1 && gkey < NN) {
                    float v = SwW[0 * 68 + quad * 16 + j];
                    patch[(size_t)(b * HH + h) * (NN - 1) + gkey - 1] = v;
                    float f = aw[b * (NN - 1) + gkey - 1] * 0.1f + 0.9f;
                    SwW[0 * 68 + quad * 16 + j] = v * f;
                }
            }
        }

        // ---- online softmax: lane owns row l16, keys quad*16..+15 ----
        const float* Srow = &SwW[l16 * 68];
        float tm = -1.0e30f;
        #pragma unroll
        for (int j = 0; j < 16; ++j) tm = fmaxf(tm, Srow[quad * 16 + j]);
        tm = fmaxf(tm, __shfl_xor(tm, 16));
        tm = fmaxf(tm, __shfl_xor(tm, 32));
        float nm = fmaxf(mst, tm);
        float alpha = __expf(mst - nm);     // first tile: exp(-1e30) -> 0
        mst = nm;
        float rsum = 0.f;
        #pragma unroll
        for (int j = 0; j < 16; ++j) {
            float p = __expf(Srow[quad * 16 + j] - nm);   // masked: exp(-1e30) -> 0
            Pt[wv][(quad * 16 + j) * 18 + l16] = f2b(p);
            rsum += p;
        }
        rsum += __shfl_xor(rsum, 16);
        rsum += __shfl_xor(rsum, 32);
        lst = lst * alpha + rsum;

        // ---- rescale O rows by alpha (alpha for row quad*4+r from lane quad*4+r) ----
        #pragma unroll
        for (int r = 0; r < 4; ++r) {
            float ar = __shfl(alpha, quad * 4 + r);
            #pragma unroll
            for (int ni = 0; ni < 4; ++ni) o[ni][r] *= ar;
        }

        // ---- O += P V ----
        #pragma unroll
        for (int kc = 0; kc < 2; ++kc) {
            union { bf16x8 v; unsigned short u[8]; } af;
            #pragma unroll
            for (int j = 0; j < 8; ++j)
                af.u[j] = Pt[wv][(kc * 32 + quad * 8 + j) * 18 + l16];
            #pragma unroll
            for (int ni = 0; ni < 4; ++ni) {
                int d = ni * 16 + l16;
                int gs = (kc * 4 + quad) ^ (d >> 3);   // un-swizzle key group
                bf16x8 vf = *(const bf16x8*)&Vt[d * 72 + gs * 8];
                o[ni] = __builtin_amdgcn_mfma_f32_16x16x32_bf16(af.v, vf, o[ni], 0, 0, 0);
            }
        }
    }

    // ---- finalize: O /= l (l for row quad*4+r from lane quad*4+r), store bf16 ----
    #pragma unroll
    for (int r = 0; r < 4; ++r) {
        float lr = __shfl(lst, quad * 4 + r);
        float inv = (lr > 0.f) ? __builtin_amdgcn_rcpf(lr) : 0.f;
        int row = qt * 64 + wv * 16 + quad * 4 + r;
        if (row < NN) {
            #pragma unroll
            for (int ni = 0; ni < 4; ++ni)
                O[(size_t)(b * NN + row) * CC + h * 64 + ni * 16 + l16] = f2b(o[ni][r] * inv);
        }
    }
}

// ---------------------------------------------------------------------------
extern "C" void kernel_launch(void* const* d_in, const int* in_sizes, int n_in,
                              void* d_out, int out_size, void* d_ws, size_t ws_size,
                              hipStream_t stream) {
    const float* x       = (const float*)d_in[0];
    const float* aw      = (const float*)d_in[1];
    const float* ln1w    = (const float*)d_in[2];
    const float* ln1b    = (const float*)d_in[3];
    const float* qkvw_f  = (const float*)d_in[4];
    const float* qkvb    = (const float*)d_in[5];
    const float* projw_f = (const float*)d_in[6];
    const float* projb   = (const float*)d_in[7];
    const float* ln2w    = (const float*)d_in[8];
    const float* ln2b    = (const float*)d_in[9];
    const float* fc1w_f  = (const float*)d_in[10];
    const float* fc1b    = (const float*)d_in[11];
    const float* fc2w_f  = (const float*)d_in[12];
    const float* fc2b    = (const float*)d_in[13];

    // workspace layout (g1 aliases h_bf+qkv, both dead before FC1). ~240 MB.
    char* ws = (char*)d_ws;
    unsigned short* h_bf  = (unsigned short*)(ws + 0);            // 18464x768 bf16
    unsigned short* qkv   = (unsigned short*)(ws + 28360704);     // 18464x2304 bf16
    unsigned short* g1    = (unsigned short*)(ws + 0);            // 18464x3072 bf16 (alias)
    unsigned short* attno = (unsigned short*)(ws + 113442816);    // 18464x768 bf16
    float*          x1    = (float*)(ws + 141803520);             // 18464x768 f32
    unsigned short* h2    = (unsigned short*)(ws + 198524928);    // 18464x768 bf16
    unsigned short* qkvw  = (unsigned short*)(ws + 226885632);    // 2304x768 bf16
    unsigned short* projw = (unsigned short*)(ws + 230424576);    // 768x768 bf16
    unsigned short* fc1w  = (unsigned short*)(ws + 231604224);    // 3072x768 bf16
    unsigned short* fc2w  = (unsigned short*)(ws + 236322816);    // 768x3072 bf16

    float* out_x = (float*)d_out;
    float* out_patch = out_x + (size_t)MROWS * CC;

    // 152 = 8 * ceil(145 m-tiles / 8) -- padded for the XCD swizzle
    cvt4<<<1024, 256, 0, stream>>>(qkvw_f, 2304 * 768, qkvw,
                                   projw_f, 768 * 768, projw,
                                   fc1w_f, 3072 * 768, fc1w,
                                   fc2w_f, 768 * 3072, fc2w);
    ln_kernel<<<MROWS, 256, 0, stream>>>(x, ln1w, ln1b, h_bf);
    gemm_bt<0><<<dim3(18, 152), 256, 0, stream>>>(h_bf, qkvw, qkvb, nullptr, qkv, nullptr,
                                                  MROWS, 2304, 768);
    attn_mfma<<<dim3(10, HH, BB), 256, 0, stream>>>(qkv, aw, attno, out_patch);
    gemm_bt<2><<<dim3(6, 152), 256, 0, stream>>>(attno, projw, projb, x, nullptr, x1,
                                                 MROWS, 768, 768);
    ln_kernel<<<MROWS, 256, 0, stream>>>(x1, ln2w, ln2b, h2);
    gemm_bt<1><<<dim3(24, 152), 256, 0, stream>>>(h2, fc1w, fc1b, nullptr, g1, nullptr,
                                                  MROWS, 3072, 768);
    gemm_bt<2><<<dim3(6, 152), 256, 0, stream>>>(g1, fc2w, fc2b, x1, nullptr, out_x,
                                                 MROWS, 768, 3072);
}